// Round 2
// baseline (101.021 us; speedup 1.0000x reference)
//
#include <hip/hip_runtime.h>

// CapsNet routing: N=32, C=32, D=16(=P*P), S=W*H=256, K=10, n_rout=3.
// FULLY FUSED, regular (non-cooperative) launch:
//   grid = 256 blocks x 1024 threads, ~124 KB static LDS/block.
//   LDS > 80 KB  =>  hardware fits at most 1 block/CU  =>  256 blocks on
//   256 CUs are ALL resident before any spin (no cooperative API needed;
//   hipLaunchCooperativeKernel is not capturable into the harness graph --
//   that's what zeroed round-1's outputs).
// Block b handles n = b>>3 and 4 channels c = (b&7)*4 + (t>>8), one
// 256-thread group per c. Cross-block coupling = per-n sum of s over 8
// blocks: device-scope atomicAdd into 3 distinct pre-zeroed buffers,
// release-scope counter increment after the block's vmcnt(0) drain
// (__syncthreads), relaxed spin + agent-scope coherent readback. No
// acquire fences in loops -> no L2 wb/inv storms.

#define KK 10
#define PP 16
#define CC 32
#define SS 256
#define NN 32
#define RR 3
#define GR 4      // channels per block
#define BPN 8     // blocks per n

__global__ __launch_bounds__(1024, 4) void fused_kernel(
    const float* __restrict__ l,       // [N][C][16][256]
    const float* __restrict__ w,       // [C][K][4][4]
    const float* __restrict__ g,       // [N][K][16]
    float* __restrict__ s_buf,         // [3][N][K*16]  pre-zeroed
    int*   __restrict__ ctr,           // [3][N]        pre-zeroed
    float* __restrict__ out_a,         // [N][K]
    float* __restrict__ out_gc)        // [N][K][16]
{
  const int bid = blockIdx.x;          // 0..255
  const int n   = bid >> 3;
  const int cg  = bid & 7;
  const int t   = threadIdx.x;         // 0..1023
  const int grp = t >> 8;              // c-group within block, 0..3
  const int tt  = t & 255;             // site index within group
  const int c   = cg * GR + grp;

  __shared__ float lr_lds[GR][PP][SS + 4];   // 66560 B
  __shared__ float ct_lds[GR][KK][SS + 4];   // 41600 B
  __shared__ float w_lds[GR][KK * PP];       //  2560 B
  __shared__ float U_lds[GR][KK * PP];       //  2560 B  (U; reused for M)
  __shared__ float pmerge[GR][4][KK * PP];   // 10240 B  per-wave M partials
  __shared__ float sred[GR][KK * PP];        //  2560 B  per-group s partials
  __shared__ float gc_lds[KK * PP];          //   640 B  shared: same n
  __shared__ float f_lds[KK];                //    40 B
  // total ~126.8 KB  ->  exactly 1 block/CU

  // ---- stage w[c], l slice (regs + LDS), g  -- ONCE for all rounds ----
  if (tt < KK * PP) w_lds[grp][tt] = w[c * KK * PP + tt];
  float lr[PP];
  const float* lb = l + (size_t)(n * CC + c) * (PP * SS) + tt;
  #pragma unroll
  for (int d = 0; d < PP; ++d) {
    lr[d] = lb[d * SS];                 // coalesced across tt
    lr_lds[grp][d][tt] = lr[d];
  }
  if (t < KK * PP) gc_lds[t] = g[n * KK * PP + t];
  __syncthreads();

  #pragma unroll 1
  for (int r = 0; r < RR; ++r) {
    if (r > 0) {
      // gc_lds holds raw s_prev (coherent readback from previous round)
      if (t < KK) {
        float sn = 0.f;
        #pragma unroll
        for (int m = 0; m < PP; ++m) { const float v = gc_lds[t * PP + m]; sn += v * v; }
        f_lds[t] = sn / (1.f + sn) * rsqrtf(sn);
      }
      __syncthreads();
      if (t < KK * PP) gc_lds[t] *= f_lds[t >> 4];
      __syncthreads();
    }

    // ---- U[k][i*4+j] = sum_dd w[c,k,j,dd] * gc[k,i*4+dd] ----
    if (tt < KK * PP) {
      const int k = tt >> 4, ij = tt & 15, i = ij >> 2, j = ij & 3;
      const float4 wv = *(const float4*)&w_lds[grp][k * PP + j * 4];
      const float4 gv = *(const float4*)&gc_lds[k * PP + i * 4];
      U_lds[grp][tt] = wv.x * gv.x + wv.y * gv.y + wv.z * gv.z + wv.w * gv.w;
    }
    __syncthreads();

    // ---- b[k] = lr . U[k]; softmax over k; store ct[k][s] ----
    {
      float b[KK];
      float bmax = -1e30f;
      #pragma unroll
      for (int k = 0; k < KK; ++k) {
        float acc = 0.f;
        #pragma unroll
        for (int d4 = 0; d4 < 4; ++d4) {
          const float4 uv = *(const float4*)&U_lds[grp][k * PP + d4 * 4]; // wave-uniform: broadcast
          acc += lr[d4*4+0]*uv.x + lr[d4*4+1]*uv.y + lr[d4*4+2]*uv.z + lr[d4*4+3]*uv.w;
        }
        b[k] = acc;
        bmax = fmaxf(bmax, acc);
      }
      float ssum = 0.f;
      #pragma unroll
      for (int k = 0; k < KK; ++k) { b[k] = __expf(b[k] - bmax); ssum += b[k]; }
      const float inv = 1.f / ssum;
      #pragma unroll
      for (int k = 0; k < KK; ++k) ct_lds[grp][k][tt] = b[k] * inv;
    }
    __syncthreads();

    // ---- M[k][ij]: 16-site chunks, reg accs, wave-shuffle chunk merge ----
    {
      const int ch = tt >> 4, ij = tt & 15, sbase = ch * 16;
      float acc[KK];
      #pragma unroll
      for (int k = 0; k < KK; ++k) acc[k] = 0.f;
      #pragma unroll
      for (int s4 = 0; s4 < 4; ++s4) {
        const float4 lv = *(const float4*)&lr_lds[grp][ij][sbase + s4 * 4];
        #pragma unroll
        for (int k = 0; k < KK; ++k) {
          const float4 cv = *(const float4*)&ct_lds[grp][k][sbase + s4 * 4]; // 16-lane broadcast
          acc[k] += cv.x*lv.x + cv.y*lv.y + cv.z*lv.z + cv.w*lv.w;
        }
      }
      // wave holds chunks {4w..4w+3}: xor over lane bits 4,5 merges them
      #pragma unroll
      for (int k = 0; k < KK; ++k) {
        acc[k] += __shfl_xor(acc[k], 16);
        acc[k] += __shfl_xor(acc[k], 32);
      }
      const int wv = tt >> 6;
      if ((tt & 63) < 16) {
        #pragma unroll
        for (int k = 0; k < KK; ++k) pmerge[grp][wv][k * PP + ij] = acc[k];
      }
    }
    __syncthreads();

    // ---- merge the 4 waves' partials -> M (into U_lds, U is dead) ----
    if (tt < KK * PP) {
      U_lds[grp][tt] = pmerge[grp][0][tt] + pmerge[grp][1][tt]
                     + pmerge[grp][2][tt] + pmerge[grp][3][tt];
    }
    __syncthreads();

    // ---- s-partial[k][i*4+d] = sum_j M[k][i*4+j]*w[c,k,j,d] ----
    if (tt < KK * PP) {
      const int k = tt >> 4, i = (tt >> 2) & 3, d = tt & 3;
      const float* Mp  = &U_lds[grp][k * PP + i * 4];
      const float* wpt = &w_lds[grp][k * PP + d];
      sred[grp][tt] = Mp[0]*wpt[0] + Mp[1]*wpt[4] + Mp[2]*wpt[8] + Mp[3]*wpt[12];
    }
    __syncthreads();

    // ---- block-local 4-channel reduce, then ONE atomicAdd per element ----
    float* s_r = s_buf + (size_t)r * NN * KK * PP;
    if (t < KK * PP) {
      atomicAdd(&s_r[n * KK * PP + t],
                sred[0][t] + sred[1][t] + sred[2][t] + sred[3][t]);
    }
    __syncthreads();   // per-wave vmcnt(0): this block's atomics are at the
                       // coherence point before t0 signals

    if (t == 0)
      __hip_atomic_fetch_add(&ctr[r * NN + n], 1,
                             __ATOMIC_RELEASE, __HIP_MEMORY_SCOPE_AGENT);

    if (r < RR - 1) {
      // per-n barrier over the 8 sibling blocks (guarded: no infinite hang)
      if (t == 0) {
        int guard = 0;
        while (__hip_atomic_load(&ctr[r * NN + n],
                                 __ATOMIC_RELAXED, __HIP_MEMORY_SCOPE_AGENT) < BPN
               && ++guard < (1 << 24))
          __builtin_amdgcn_s_sleep(2);
      }
      __syncthreads();
      if (t < KK * PP)
        gc_lds[t] = __hip_atomic_load(&s_r[n * KK * PP + t],
                                      __ATOMIC_RELAXED, __HIP_MEMORY_SCOPE_AGENT);
      __syncthreads();
    }
  }

  // ---- final outputs: one block per n (cg==0) ----
  if (cg == 0) {
    float* s2 = s_buf + (size_t)2 * NN * KK * PP;
    if (t == 0) {
      int guard = 0;
      while (__hip_atomic_load(&ctr[2 * NN + n],
                               __ATOMIC_RELAXED, __HIP_MEMORY_SCOPE_AGENT) < BPN
             && ++guard < (1 << 24))
        __builtin_amdgcn_s_sleep(2);
    }
    __syncthreads();
    if (t < KK * PP)
      gc_lds[t] = __hip_atomic_load(&s2[n * KK * PP + t],
                                    __ATOMIC_RELAXED, __HIP_MEMORY_SCOPE_AGENT);
    __syncthreads();
    if (t < KK) {
      float sn = 0.f;
      #pragma unroll
      for (int m = 0; m < PP; ++m) { const float v = gc_lds[t * PP + m]; sn += v * v; }
      f_lds[t] = sn / (1.f + sn) * rsqrtf(sn);
      const float gn = sn / (1.f + sn);          // = sqrt(sum gc^2)
      out_a[n * KK + t] = 1.f / (1.f + __expf(-gn));
    }
    __syncthreads();
    if (t < KK * PP) out_gc[n * KK * PP + t] = gc_lds[t] * f_lds[t >> 4];
  }
}

extern "C" void kernel_launch(void* const* d_in, const int* in_sizes, int n_in,
                              void* d_out, int out_size, void* d_ws, size_t ws_size,
                              hipStream_t stream) {
  const float* l = (const float*)d_in[0];
  const float* g = (const float*)d_in[1];
  const float* w = (const float*)d_in[2];

  float* out    = (float*)d_out;
  float* out_a  = out;
  float* out_gc = out + NN * KK;

  float* s_buf = (float*)d_ws;                           // [3][N][160]
  int*   ctr   = (int*)((char*)d_ws +
                        (size_t)3 * NN * KK * PP * sizeof(float)); // [3][N]
  const size_t zero_bytes =
      (size_t)3 * NN * KK * PP * sizeof(float) + (size_t)3 * NN * sizeof(int);
  hipMemsetAsync(d_ws, 0, zero_bytes, stream);

  fused_kernel<<<NN * BPN, 1024, 0, stream>>>(l, w, g, s_buf, ctr,
                                              out_a, out_gc);
}